// Round 1
// baseline (405.026 us; speedup 1.0000x reference)
//
#include <hip/hip_runtime.h>
#include <stdint.h>

// Problem constants: x [B=2, S=4096, K=4096] -> M = 8192; weight [N=4096, K=4096]
#define M_DIM 8192
#define N_DIM 4096
#define K_DIM 4096

using int4v = __attribute__((ext_vector_type(4))) int;

// ---------------------------------------------------------------------------
// Pack kernel: int32 (widened int8 in [-127,127]) -> int8 bytes.
// ---------------------------------------------------------------------------
__global__ __launch_bounds__(256) void pack_kernel(const int4* __restrict__ sx,
                                                   const int4* __restrict__ sw,
                                                   unsigned int* __restrict__ dst,
                                                   int nx, int ntot) {
    int idx = blockIdx.x * blockDim.x + threadIdx.x;
    if (idx >= ntot) return;
    int4 v = (idx < nx) ? sx[idx] : sw[idx - nx];
    dst[idx] = (v.x & 0xff) | ((v.y & 0xff) << 8) | ((v.z & 0xff) << 16) |
               ((v.w & 0xff) << 24);
}

// ---------------------------------------------------------------------------
// Async global -> LDS copy, 16 B per lane (global_load_lds_dwordx4).
// ---------------------------------------------------------------------------
__device__ __forceinline__ void async_copy16(const char* g, char* l) {
    __builtin_amdgcn_global_load_lds(
        (const __attribute__((address_space(1))) char*)g,
        (__attribute__((address_space(3))) char*)l, 16, 0, 0);
}

// ---------------------------------------------------------------------------
// 256x256 8-phase i8 GEMM (T1+T2+T3+T4+T5 port of the verified bf16 template).
// 512 threads = 8 waves (2M x 4N); per-wave 128x64 output = 8x4 grid of 16x16
// MFMA tiles (mfma_i32_16x16x64_i8), BK = 128 bytes (2 k-substeps of 64).
// LDS: 2 dbuf x (A 256x128 + B 256x128) = 128 KiB -> 1 block/CU.
//
// Per K-tile, 4 phases (one C-quadrant each, 16 MFMA):
//   ph a: read A[m0..3]x2k + B[n0..1]x2k (12 ds_read_b128)  -> MM(0,0)
//   ph b: read B[n2..3]x2k (4)                              -> MM(0,1)
//   ph c: read A[m4..7]x2k (8)                              -> MM(1,0)
//   ph d: (no reads)                                        -> MM(1,1)
// Staging (counted vmcnt, never 0 in main loop): iter i computes tiles 2i,2i+1
//   ph1: A.h1(t1)  ph2: B.h0+B.h1(t1)  ph4: A.h0(t2)+vmcnt(2)
//   ph5: A.h1(t2)  ph6: B.h0+B.h1(t2)  ph8: A.h0(t3)+vmcnt(2)
// Every waited-on load was issued >=2 phases earlier; 2-10 loads always in
// flight across barriers (the m97 structure's vmcnt(0) drain is eliminated).
//
// LDS swizzle: 16-B chunk (row, cg) stored at cg ^ ((row>>1)&7) (8 col-groups
// per 128-B row). ds_read_b128 fans 16 lanes across 8 bank-groups (2-way =
// free); global_load_lds stays linear, the XOR is folded into the global
// source address (both-sides-or-neither rule).
// ---------------------------------------------------------------------------
__global__ __launch_bounds__(512, 2) void gemm_i8_kernel(
    const char* __restrict__ Aq,   // [M, K] int8
    const char* __restrict__ Bq,   // [N, K] int8
    const int* __restrict__ bias,  // [N] int32 (widened int8)
    const float* __restrict__ a_ptr,
    const float* __restrict__ b_ptr,
    int32_t* __restrict__ out)     // [M, N] int32 holding int8 values
{
    __shared__ char As[2][256 * 128];   // 2 x 32 KiB
    __shared__ char Bs[2][256 * 128];   // 2 x 32 KiB

    const int tid  = threadIdx.x;
    const int lane = tid & 63;
    const int wave = tid >> 6;
    const int wr   = wave >> 2;   // 0..1 -> 128 M-rows
    const int wc   = wave & 3;    // 0..3 -> 64 N-cols

    // T1: bijective XCD swizzle (512 blocks % 8 == 0). Consecutive local ids
    // share the same B panel (1 MiB -> L2-resident per XCD).
    const int bid    = blockIdx.x;
    const int swzb   = (bid & 7) * 64 + (bid >> 3);
    const int tile_m = swzb & 31;          // 32 M-tiles
    const int tile_n = swzb >> 5;          // 16 N-tiles
    const int m0 = tile_m * 256;
    const int n0 = tile_n * 256;

    const float alpha = *a_ptr;
    const float beta  = *b_ptr;

    int4v acc[8][4] = {};   // 128 accumulator regs
    int4v rA[8], rB0[4], rB1[4];

    // Fragment read coords: lane holds op row m = lane&15, k-group = lane>>4.
    const int fr = lane & 15;
    const int gw = lane >> 4;
    const int swz = (fr >> 1) & 7;
    const int k0off = (gw ^ swz) << 4;          // k-substep 0
    const int k1off = ((4 + gw) ^ swz) << 4;    // k-substep 1
    const int arow = wr * 128 + fr;
    const int brow = wc * 64 + fr;

    // Staging: thread t owns chunks c = t and c = t+512 of each 128-row half
    // (row = c>>3, stored col-group = c&7, global cg = (c&7) ^ ((c>>4)&7)).
    const int srow = tid >> 3;                               // 0..63
    const int scg  = ((tid & 7) ^ ((tid >> 4) & 7)) << 4;    // byte col offset
    const char* gA0 = Aq + (size_t)(m0 + srow) * K_DIM + scg;
    const char* gA1 = gA0 + (size_t)64 * K_DIM;
    const char* gB0 = Bq + (size_t)(n0 + srow) * K_DIM + scg;
    const char* gB1 = gB0 + (size_t)64 * K_DIM;

#define STAGE_A(buf, h, t)                                                   \
    do {                                                                     \
        const size_t off_ = (size_t)(h) * (128 * K_DIM) + (size_t)(t) * 128; \
        char* l_ = &As[buf][(h)*16384 + (tid << 4)];                         \
        async_copy16(gA0 + off_, l_);                                        \
        async_copy16(gA1 + off_, l_ + 8192);                                 \
    } while (0)

#define STAGE_B(buf, h, t)                                                   \
    do {                                                                     \
        const size_t off_ = (size_t)(h) * (128 * K_DIM) + (size_t)(t) * 128; \
        char* l_ = &Bs[buf][(h)*16384 + (tid << 4)];                         \
        async_copy16(gB0 + off_, l_);                                        \
        async_copy16(gB1 + off_, l_ + 8192);                                 \
    } while (0)

#define DS_A(qm)                                                             \
    do {                                                                     \
        _Pragma("unroll") for (int ii = 0; ii < 4; ++ii) {                   \
            const char* p_ = &As[b][(arow + ((qm)*4 + ii) * 16) * 128];      \
            rA[ii * 2 + 0] = *(const int4v*)(p_ + k0off);                    \
            rA[ii * 2 + 1] = *(const int4v*)(p_ + k1off);                    \
        }                                                                    \
    } while (0)

#define DS_B(RB, qn)                                                         \
    do {                                                                     \
        _Pragma("unroll") for (int jj = 0; jj < 2; ++jj) {                   \
            const char* p_ = &Bs[b][(brow + ((qn)*2 + jj) * 16) * 128];      \
            RB[jj * 2 + 0] = *(const int4v*)(p_ + k0off);                    \
            RB[jj * 2 + 1] = *(const int4v*)(p_ + k1off);                    \
        }                                                                    \
    } while (0)

#define MM(qm, qn, RB)                                                       \
    do {                                                                     \
        _Pragma("unroll") for (int ii = 0; ii < 4; ++ii)                     \
        _Pragma("unroll") for (int jj = 0; jj < 2; ++jj)                     \
        _Pragma("unroll") for (int kk = 0; kk < 2; ++kk)                     \
            acc[(qm)*4 + ii][(qn)*2 + jj] =                                  \
                __builtin_amdgcn_mfma_i32_16x16x64_i8(                       \
                    rA[ii * 2 + kk], RB[jj * 2 + kk],                        \
                    acc[(qm)*4 + ii][(qn)*2 + jj], 0, 0, 0);                 \
    } while (0)

#define PH_OPEN                                                              \
    __builtin_amdgcn_s_barrier();                                            \
    asm volatile("s_waitcnt lgkmcnt(0)" ::: "memory");                       \
    __builtin_amdgcn_sched_barrier(0);                                       \
    __builtin_amdgcn_s_setprio(1)

#define PH_CLOSE                                                             \
    __builtin_amdgcn_s_setprio(0);                                           \
    __builtin_amdgcn_s_barrier();                                            \
    __builtin_amdgcn_sched_barrier(0)

#define PH_CLOSE_VM(n)                                                       \
    __builtin_amdgcn_s_setprio(0);                                           \
    asm volatile("s_waitcnt vmcnt(" #n ")" ::: "memory");                    \
    __builtin_amdgcn_s_barrier();                                            \
    __builtin_amdgcn_sched_barrier(0)

    // Prologue: tile 0 complete + A.h0 of tile 1 in flight.
    STAGE_A(0, 0, 0);
    STAGE_A(0, 1, 0);
    STAGE_B(0, 0, 0);
    STAGE_B(0, 1, 0);
    STAGE_A(1, 0, 1);
    asm volatile("s_waitcnt vmcnt(2)" ::: "memory");
    __builtin_amdgcn_s_barrier();
    __builtin_amdgcn_sched_barrier(0);

#pragma unroll 1
    for (int it = 0; it < 15; ++it) {
        const int t1 = 2 * it + 1;
        const int t2 = 2 * it + 2;
        const int t3 = 2 * it + 3;
        {   // ph1: tile 2i, quadrant (0,0)
            const int b = 0;
            DS_A(0); DS_B(rB0, 0);
            STAGE_A(1, 1, t1);
            PH_OPEN; MM(0, 0, rB0); PH_CLOSE;
        }
        {   // ph2: quadrant (0,1)
            const int b = 0;
            DS_B(rB1, 1);
            STAGE_B(1, 0, t1);
            STAGE_B(1, 1, t1);
            PH_OPEN; MM(0, 1, rB1); PH_CLOSE;
        }
        {   // ph3: quadrant (1,0)
            const int b = 0;
            DS_A(1);
            PH_OPEN; MM(1, 0, rB0); PH_CLOSE;
        }
        {   // ph4: quadrant (1,1); buf0 A fully read -> restage; tile t1 must land
            STAGE_A(0, 0, t2);
            __builtin_amdgcn_s_barrier();
            __builtin_amdgcn_s_setprio(1);
            MM(1, 1, rB1);
            PH_CLOSE_VM(2);
        }
        {   // ph5: tile 2i+1, quadrant (0,0)
            const int b = 1;
            DS_A(0); DS_B(rB0, 0);
            STAGE_A(0, 1, t2);
            PH_OPEN; MM(0, 0, rB0); PH_CLOSE;
        }
        {   // ph6
            const int b = 1;
            DS_B(rB1, 1);
            STAGE_B(0, 0, t2);
            STAGE_B(0, 1, t2);
            PH_OPEN; MM(0, 1, rB1); PH_CLOSE;
        }
        {   // ph7
            const int b = 1;
            DS_A(1);
            PH_OPEN; MM(1, 0, rB0); PH_CLOSE;
        }
        {   // ph8: buf1 A fully read -> restage; tile t2 must land
            STAGE_A(1, 0, t3);
            __builtin_amdgcn_s_barrier();
            __builtin_amdgcn_s_setprio(1);
            MM(1, 1, rB1);
            PH_CLOSE_VM(2);
        }
    }

    // Epilogue tile 30 (buf0): finish staging tile 31, final drain.
    {
        const int b = 0;
        {
            DS_A(0); DS_B(rB0, 0);
            STAGE_A(1, 1, 31);
            PH_OPEN; MM(0, 0, rB0); PH_CLOSE;
        }
        {
            DS_B(rB1, 1);
            STAGE_B(1, 0, 31);
            STAGE_B(1, 1, 31);
            PH_OPEN; MM(0, 1, rB1); PH_CLOSE;
        }
        {
            DS_A(1);
            PH_OPEN; MM(1, 0, rB0); PH_CLOSE;
        }
        {
            __builtin_amdgcn_s_barrier();
            __builtin_amdgcn_s_setprio(1);
            MM(1, 1, rB1);
            PH_CLOSE_VM(0);
        }
    }
    // Epilogue tile 31 (buf1): all data resident, no barriers needed.
    {
        const int b = 1;
        DS_A(0); DS_B(rB0, 0); DS_B(rB1, 1);
        asm volatile("s_waitcnt lgkmcnt(0)" ::: "memory");
        __builtin_amdgcn_sched_barrier(0);
        MM(0, 0, rB0); MM(0, 1, rB1);
        DS_A(1);
        asm volatile("s_waitcnt lgkmcnt(0)" ::: "memory");
        __builtin_amdgcn_sched_barrier(0);
        MM(1, 0, rB0); MM(1, 1, rB1);
    }

    // Epilogue: C/D layout col = lane&15, row = (lane>>4)*4 + reg.
    const int orow = (lane >> 4) * 4;
    const int ocol = lane & 15;
#pragma unroll
    for (int j = 0; j < 4; ++j) {
        const int gn = n0 + wc * 64 + j * 16 + ocol;
        const float bb = beta * (float)bias[gn];
#pragma unroll
        for (int i = 0; i < 8; ++i) {
            const int gm = m0 + wr * 128 + i * 16 + orow;
#pragma unroll
            for (int r = 0; r < 4; ++r) {
                float v = alpha * (float)acc[i][j][r] + bb;
                v = rintf(v);                       // round half-to-even (numpy)
                v = fminf(fmaxf(v, -128.0f), 127.0f);
                out[(size_t)(gm + r) * N_DIM + gn] = (int32_t)v;
            }
        }
    }
}

// ---------------------------------------------------------------------------
extern "C" void kernel_launch(void* const* d_in, const int* in_sizes, int n_in,
                              void* d_out, int out_size, void* d_ws, size_t ws_size,
                              hipStream_t stream) {
    const int*   x    = (const int*)d_in[0];    // [M, K] widened int8
    const int*   w    = (const int*)d_in[1];    // [N, K] widened int8
    const int*   bias = (const int*)d_in[2];    // [N]
    const float* a    = (const float*)d_in[3];  // alpha scalar
    const float* b    = (const float*)d_in[4];  // beta scalar
    int32_t*     out  = (int32_t*)d_out;        // [M, N]

    char* xq = (char*)d_ws;                     // 32 MiB packed x
    const int nx   = (M_DIM * K_DIM) / 4;       // int4-groups in x
    const int nw   = (N_DIM * K_DIM) / 4;
    const int ntot = nx + nw;
    pack_kernel<<<(ntot + 255) / 256, 256, 0, stream>>>(
        (const int4*)x, (const int4*)w, (unsigned int*)xq, nx, ntot);

    char* wq = xq + (size_t)M_DIM * K_DIM;      // 16 MiB packed weight

    dim3 grid((M_DIM / 256) * (N_DIM / 256));   // 512 blocks, 1D for XCD swizzle
    gemm_i8_kernel<<<grid, 512, 0, stream>>>(xq, wq, bias, a, b, out);
}

// Round 2
// 394.859 us; speedup vs baseline: 1.0258x; 1.0258x over previous
//
#include <hip/hip_runtime.h>
#include <stdint.h>

// Problem constants: x [B=2, S=4096, K=4096] -> M = 8192; weight [N=4096, K=4096]
#define M_DIM 8192
#define N_DIM 4096
#define K_DIM 4096

using int4v = __attribute__((ext_vector_type(4))) int;

// ---------------------------------------------------------------------------
// Pack kernel: int32 (widened int8 in [-127,127]) -> int8 bytes.
// ---------------------------------------------------------------------------
__global__ __launch_bounds__(256) void pack_kernel(const int4* __restrict__ sx,
                                                   const int4* __restrict__ sw,
                                                   unsigned int* __restrict__ dst,
                                                   int nx, int ntot) {
    int idx = blockIdx.x * blockDim.x + threadIdx.x;
    if (idx >= ntot) return;
    int4 v = (idx < nx) ? sx[idx] : sw[idx - nx];
    dst[idx] = (v.x & 0xff) | ((v.y & 0xff) << 8) | ((v.z & 0xff) << 16) |
               ((v.w & 0xff) << 24);
}

// ---------------------------------------------------------------------------
// Async global -> LDS copy, 16 B per lane (global_load_lds_dwordx4).
// ---------------------------------------------------------------------------
__device__ __forceinline__ void async_copy16(const char* g, char* l) {
    __builtin_amdgcn_global_load_lds(
        (const __attribute__((address_space(1))) char*)g,
        (__attribute__((address_space(3))) char*)l, 16, 0, 0);
}

// ---------------------------------------------------------------------------
// 256x256 i8 GEMM, ONE barrier pair per 128-B K-tile (r2).
// R1 post-mortem: per-phase barriers serialized LDS pipe (2800 cyc/K-tile)
// against MFMA pipe (2612 cyc) -> 6000 cyc/K-tile measured. This version
// gives the compiler a whole K-tile body (24 ds_read_b128 + 64 MFMA) to
// schedule with counted lgkmcnt (m97 evidence: compiler is near-optimal at
// this), so the two pipes overlap. Staging for tile t+1 is issued at the TOP
// of tile t (into the other buffer) and drained with vmcnt(0) at the BOTTOM:
// ~2600 cyc of compute covers HBM latency.
//
// 512 threads = 8 waves (2M x 4N); per-wave 128x64 output = 8x4 grid of
// 16x16 MFMA tiles (mfma_i32_16x16x64_i8), 2 k-substeps of 64 per K-tile.
// LDS: 2 dbuf x (A 256x128 + B 256x128) = 128 KiB -> 1 block/CU.
//
// LDS swizzle (conflict-free, measured 0): 16-B chunk (row, cg) stored at
// cg ^ ((row>>1)&7); global source pre-swizzled, reads XOR-correct.
// ---------------------------------------------------------------------------
__global__ __launch_bounds__(512, 2) void gemm_i8_kernel(
    const char* __restrict__ Aq,   // [M, K] int8
    const char* __restrict__ Bq,   // [N, K] int8
    const int* __restrict__ bias,  // [N] int32 (widened int8)
    const float* __restrict__ a_ptr,
    const float* __restrict__ b_ptr,
    int32_t* __restrict__ out)     // [M, N] int32 holding int8 values
{
    // Separate arrays per buffer -> compiler can disambiguate staging writes
    // from fragment reads (no false aliasing between the two buffers).
    __shared__ char As0[256 * 128];   // 32 KiB
    __shared__ char As1[256 * 128];
    __shared__ char Bs0[256 * 128];
    __shared__ char Bs1[256 * 128];

    const int tid  = threadIdx.x;
    const int lane = tid & 63;
    const int wave = tid >> 6;
    const int wr   = wave >> 2;   // 0..1 -> 128 M-rows
    const int wc   = wave & 3;    // 0..3 -> 64 N-cols

    // T1: XCD swizzle with SQUARE 8x8 chunks (r1's column chunks touched all
    // of A per XCD -> 270 MB HBM fetch). Each XCD: 8 M-tiles x 8 N-tiles =
    // 8 MB A + 8 MB B; each A panel hit by 2 XCDs, B by 4 (L3 absorbs).
    const int bid = blockIdx.x;
    const int xcd = bid & 7;      // dispatch round-robins XCDs
    const int lin = bid >> 3;     // 0..63 within this XCD's chunk
    const int m0  = ((xcd & 3) * 8 + (lin & 7)) * 256;   // 32 M-tiles
    const int n0  = ((xcd >> 2) * 8 + (lin >> 3)) * 256; // 16 N-tiles

    const float alpha = *a_ptr;
    const float beta  = *b_ptr;

    int4v acc[8][4] = {};   // 128 accumulator regs (AGPR)

    // Fragment read coords: lane holds op row m = lane&15, k-group = lane>>4.
    const int fr = lane & 15;
    const int gw = lane >> 4;
    const int swz = (fr >> 1) & 7;
    const int k0off = (gw ^ swz) << 4;          // k-substep 0
    const int k1off = ((4 + gw) ^ swz) << 4;    // k-substep 1
    const int arow = wr * 128 + fr;
    const int brow = wc * 64 + fr;

    // Staging: thread t owns chunk (row = t>>3, stored cg = t&7); global
    // cg = (t&7) ^ ((t>>4)&7) pre-applies the swizzle at the source.
    const int srow = tid >> 3;                               // 0..63
    const int scg  = ((tid & 7) ^ ((tid >> 4) & 7)) << 4;    // byte col offset
    const char* gA0 = Aq + (size_t)(m0 + srow) * K_DIM + scg;
    const char* gA1 = gA0 + (size_t)64 * K_DIM;
    const char* gB0 = Bq + (size_t)(n0 + srow) * K_DIM + scg;
    const char* gB1 = gB0 + (size_t)64 * K_DIM;

#define STAGE_A(AS, h, t)                                                    \
    {                                                                        \
        const size_t off_ = (size_t)(h) * (128 * K_DIM) + (size_t)(t) * 128; \
        char* l_ = &AS[(h)*16384 + (tid << 4)];                              \
        async_copy16(gA0 + off_, l_);                                        \
        async_copy16(gA1 + off_, l_ + 8192);                                 \
    }

#define STAGE_B(BS, h, t)                                                    \
    {                                                                        \
        const size_t off_ = (size_t)(h) * (128 * K_DIM) + (size_t)(t) * 128; \
        char* l_ = &BS[(h)*16384 + (tid << 4)];                              \
        async_copy16(gB0 + off_, l_);                                        \
        async_copy16(gB1 + off_, l_ + 8192);                                 \
    }

#define STAGE_TILE(AS, BS, t)                                                \
    {                                                                        \
        STAGE_A(AS, 0, t);                                                   \
        STAGE_A(AS, 1, t);                                                   \
        STAGE_B(BS, 0, t);                                                   \
        STAGE_B(BS, 1, t);                                                   \
    }

#define DS_A2(AS, qm)                                                        \
    {                                                                        \
        _Pragma("unroll") for (int ii = 0; ii < 4; ++ii) {                   \
            const char* pa_ = &AS[(arow + ((qm)*4 + ii) * 16) * 128];        \
            af[ii * 2 + 0] = *(const int4v*)(pa_ + k0off);                   \
            af[ii * 2 + 1] = *(const int4v*)(pa_ + k1off);                   \
        }                                                                    \
    }

#define DS_B2(BS, R, qn)                                                     \
    {                                                                        \
        _Pragma("unroll") for (int jj = 0; jj < 2; ++jj) {                   \
            const char* pb_ = &BS[(brow + ((qn)*2 + jj) * 16) * 128];        \
            R[jj * 2 + 0] = *(const int4v*)(pb_ + k0off);                    \
            R[jj * 2 + 1] = *(const int4v*)(pb_ + k1off);                    \
        }                                                                    \
    }

#define MM2(qm, qn, RB)                                                      \
    {                                                                        \
        _Pragma("unroll") for (int ii = 0; ii < 4; ++ii)                     \
        _Pragma("unroll") for (int jj = 0; jj < 2; ++jj)                     \
        _Pragma("unroll") for (int kk = 0; kk < 2; ++kk)                     \
            acc[(qm)*4 + ii][(qn)*2 + jj] =                                  \
                __builtin_amdgcn_mfma_i32_16x16x64_i8(                       \
                    af[ii * 2 + kk], RB[jj * 2 + kk],                        \
                    acc[(qm)*4 + ii][(qn)*2 + jj], 0, 0, 0);                 \
    }

    // Whole K-tile body: compiler schedules 24 ds_read_b128 against 64 MFMA
    // with counted lgkm waits (quadrant order keeps consecutive MFMA groups
    // on independent acc registers; af is reloaded mid-body -> mild WAR the
    // allocator can rename within budget).
#define COMPUTE_TILE(AS, BS)                                                 \
    {                                                                        \
        int4v af[8], bf0[4], bf1[4];                                         \
        DS_A2(AS, 0);                                                        \
        DS_B2(BS, bf0, 0);                                                   \
        DS_B2(BS, bf1, 1);                                                   \
        __builtin_amdgcn_s_setprio(1);                                       \
        MM2(0, 0, bf0);                                                      \
        MM2(0, 1, bf1);                                                      \
        DS_A2(AS, 1);                                                        \
        MM2(1, 0, bf0);                                                      \
        MM2(1, 1, bf1);                                                      \
        __builtin_amdgcn_s_setprio(0);                                       \
    }

    // Tile boundary: drain this tile's 8 staging loads (issued ~2600 cyc ago,
    // nearly free), then block barrier. Trailing sched_barrier(0) stops the
    // next tile's ds_reads from hoisting above the barrier.
#define TILE_END                                                             \
    {                                                                        \
        asm volatile("s_waitcnt vmcnt(0)" ::: "memory");                     \
        __builtin_amdgcn_s_barrier();                                        \
        __builtin_amdgcn_sched_barrier(0);                                   \
    }

    // Prologue: stage tile 0 into buf0 (latency exposed once).
    STAGE_TILE(As0, Bs0, 0);
    TILE_END;

#pragma unroll 1
    for (int it = 0; it < 15; ++it) {
        const int t1 = 2 * it + 1;
        const int t2 = 2 * it + 2;
        // tile 2it (buf0): stage tile t1 -> buf1 first (issue early).
        STAGE_TILE(As1, Bs1, t1);
        __builtin_amdgcn_sched_barrier(0);   // pin stage issue before compute
        COMPUTE_TILE(As0, Bs0);
        TILE_END;
        // tile 2it+1 (buf1): stage tile t2 -> buf0.
        STAGE_TILE(As0, Bs0, t2);
        __builtin_amdgcn_sched_barrier(0);
        COMPUTE_TILE(As1, Bs1);
        TILE_END;
    }
    // Tile 30 (buf0): stage final tile 31 -> buf1.
    STAGE_TILE(As1, Bs1, 31);
    __builtin_amdgcn_sched_barrier(0);
    COMPUTE_TILE(As0, Bs0);
    TILE_END;
    // Tile 31 (buf1): compute only.
    COMPUTE_TILE(As1, Bs1);

    // Epilogue: C/D layout col = lane&15, row = (lane>>4)*4 + reg.
    const int orow = (lane >> 4) * 4;
    const int ocol = lane & 15;
#pragma unroll
    for (int j = 0; j < 4; ++j) {
        const int gn = n0 + wc * 64 + j * 16 + ocol;
        const float bb = beta * (float)bias[gn];
#pragma unroll
        for (int i = 0; i < 8; ++i) {
            const int gm = m0 + wr * 128 + i * 16 + orow;
#pragma unroll
            for (int r = 0; r < 4; ++r) {
                float v = alpha * (float)acc[i][j][r] + bb;
                v = rintf(v);                       // round half-to-even (numpy)
                v = fminf(fmaxf(v, -128.0f), 127.0f);
                out[(size_t)(gm + r) * N_DIM + gn] = (int32_t)v;
            }
        }
    }
}

// ---------------------------------------------------------------------------
extern "C" void kernel_launch(void* const* d_in, const int* in_sizes, int n_in,
                              void* d_out, int out_size, void* d_ws, size_t ws_size,
                              hipStream_t stream) {
    const int*   x    = (const int*)d_in[0];    // [M, K] widened int8
    const int*   w    = (const int*)d_in[1];    // [N, K] widened int8
    const int*   bias = (const int*)d_in[2];    // [N]
    const float* a    = (const float*)d_in[3];  // alpha scalar
    const float* b    = (const float*)d_in[4];  // beta scalar
    int32_t*     out  = (int32_t*)d_out;        // [M, N]

    char* xq = (char*)d_ws;                     // 32 MiB packed x
    const int nx   = (M_DIM * K_DIM) / 4;       // int4-groups in x
    const int nw   = (N_DIM * K_DIM) / 4;
    const int ntot = nx + nw;
    pack_kernel<<<(ntot + 255) / 256, 256, 0, stream>>>(
        (const int4*)x, (const int4*)w, (unsigned int*)xq, nx, ntot);

    char* wq = xq + (size_t)M_DIM * K_DIM;      // 16 MiB packed weight

    dim3 grid((M_DIM / 256) * (N_DIM / 256));   // 512 blocks, 1D for XCD swizzle
    gemm_i8_kernel<<<grid, 512, 0, stream>>>(xq, wq, bias, a, b, out);
}